// Round 1
// baseline (20950.203 us; speedup 1.0000x reference)
//
#include <hip/hip_runtime.h>
#include <hip/hip_bf16.h>
#include <hip/hip_cooperative_groups.h>

namespace cg = cooperative_groups;

#define B_DIM 128
#define T_DIM 512
#define I_DIMV 256
#define H_DIM 1024
#define G_DIM 4096
#define K_TOT 1280
#define C_DIM 1000

typedef __attribute__((ext_vector_type(8))) short short8;
typedef __attribute__((ext_vector_type(4))) float f32x4;
typedef __attribute__((ext_vector_type(4))) unsigned short ushort4v;

__device__ __forceinline__ unsigned short f2bf(float f) {
    unsigned int u = __float_as_uint(f);
    u += 0x7FFF + ((u >> 16) & 1);   // round-to-nearest-even
    return (unsigned short)(u >> 16);
}

__device__ __forceinline__ float sigmoid_f(float x) {
    return __builtin_amdgcn_rcpf(1.0f + __expf(-x));
}
__device__ __forceinline__ float tanh_f(float x) {
    // (e^{2x}-1)/(e^{2x}+1); saturates correctly for |x| large
    return 1.0f - 2.0f * __builtin_amdgcn_rcpf(1.0f + __expf(2.0f * x));
}

// ---------------------------------------------------------------------------
// Prologue: build combined bf16 weight matrix Wc[p][k] (p = j*4+q interleave,
// k<1024 -> W_hh, k>=1024 -> W_ih), combined bias, x in bf16, zero h buffer.
// Runs every call (ws is re-poisoned before every timed launch).
// ---------------------------------------------------------------------------
__global__ void prep_kernel(const float* __restrict__ x,
                            const float* __restrict__ Wih,
                            const float* __restrict__ Whh,
                            const float* __restrict__ bih,
                            const float* __restrict__ bhh,
                            unsigned short* __restrict__ Wc,
                            unsigned short* __restrict__ xbf,
                            float* __restrict__ biasc,
                            unsigned short* __restrict__ h0)
{
    const int tid = blockIdx.x * blockDim.x + threadIdx.x;
    const int nth = gridDim.x * blockDim.x;

    const int WcN4 = G_DIM * K_TOT / 4;          // 1,310,720 vec4 chunks
    for (int i = tid; i < WcN4; i += nth) {
        int p = i / (K_TOT / 4);                 // const divisor -> magic mul
        int k = (i - p * (K_TOT / 4)) * 4;
        int j = p >> 2, q = p & 3;
        int r = q * H_DIM + j;                   // original gate row
        const float* src = (k < H_DIM) ? (Whh + (size_t)r * H_DIM + k)
                                       : (Wih + (size_t)r * I_DIMV + (k - H_DIM));
        f32x4 v = *(const f32x4*)src;
        ushort4v o;
        o.x = f2bf(v.x); o.y = f2bf(v.y); o.z = f2bf(v.z); o.w = f2bf(v.w);
        *(ushort4v*)(Wc + (size_t)i * 4) = o;
    }
    const int xN4 = B_DIM * T_DIM * I_DIMV / 4;
    for (int i = tid; i < xN4; i += nth) {
        f32x4 v = *(const f32x4*)(x + (size_t)i * 4);
        ushort4v o;
        o.x = f2bf(v.x); o.y = f2bf(v.y); o.z = f2bf(v.z); o.w = f2bf(v.w);
        *(ushort4v*)(xbf + (size_t)i * 4) = o;
    }
    for (int p = tid; p < G_DIM; p += nth) {
        int j = p >> 2, q = p & 3;
        int r = q * H_DIM + j;
        biasc[p] = bih[r] + bhh[r];
    }
    const int hN4 = B_DIM * H_DIM / 4;
    for (int i = tid; i < hN4; i += nth) {
        ushort4v z = {0, 0, 0, 0};
        *(ushort4v*)(h0 + (size_t)i * 4) = z;
    }
}

// ---------------------------------------------------------------------------
// Persistent LSTM kernel. 256 WGs x 256 threads (1 WG/CU), cooperative launch.
// WG wgid: m_blk = wgid/64 -> batch rows [32*m_blk, +32)
//          n_blk = wgid%64 -> hidden slice [16*n_blk, +16) == Wc rows [64*n_blk, +64)
// Per wave: 32(batch) x 16(gate-col) output via 2x MFMA 16x16x32 bf16, K=1280.
// c-state lives in registers for all 512 steps. One grid.sync per step.
// ---------------------------------------------------------------------------
__global__ __launch_bounds__(256, 1)
void lstm_persistent(const unsigned short* __restrict__ Wc,
                     const unsigned short* __restrict__ xbf,
                     const float* __restrict__ biasc,
                     unsigned short* __restrict__ hb0,
                     unsigned short* __restrict__ hb1,
                     float* __restrict__ hf32)
{
    __shared__ __align__(16) unsigned short Alds[32 * 136];  // 32x128, pad->136
    __shared__ __align__(16) unsigned short Wlds[64 * 136];  // 64x128, pad->136

    const int tid   = threadIdx.x;
    const int wgid  = blockIdx.x;
    const int m_blk = wgid >> 6;
    const int n_blk = wgid & 63;
    const int mb = m_blk * 32;
    const int p0 = n_blk * 64;
    const int j0 = n_blk * 16;

    const int wid  = tid >> 6;       // wave 0..3 -> n-subtile
    const int lane = tid & 63;
    const int cl   = lane & 15;
    const int quad = lane >> 4;
    const int q_g  = cl & 3;         // gate index: 0=i 1=f 2=g 3=o
    const int jl   = cl >> 2;        // hidden offset within wave's 4

    const float bias_lane = biasc[p0 + wid * 16 + cl];

    float c_reg[8];
    #pragma unroll
    for (int i = 0; i < 8; ++i) c_reg[i] = 0.0f;

    cg::grid_group grid = cg::this_grid();

    for (int t = 0; t < T_DIM; ++t) {
        const unsigned short* __restrict__ hread = (t & 1) ? hb1 : hb0;
        unsigned short* __restrict__ hwrite      = (t & 1) ? hb0 : hb1;

        f32x4 acc0 = {0.f, 0.f, 0.f, 0.f};
        f32x4 acc1 = {0.f, 0.f, 0.f, 0.f};

        for (int s = 0; s < 10; ++s) {           // K = 1280 in BK=128 chunks
            const int k0 = s * 128;
            __syncthreads();
            // stage A tile 32x128 (h for s<8, x_t for s>=8), 16B per thread x2
            #pragma unroll
            for (int u = 0; u < 2; ++u) {
                const int idx = tid + u * 256;
                const int r  = idx >> 4;
                const int kk = (idx & 15) * 8;
                const unsigned short* src =
                    (s < 8) ? (hread + (size_t)(mb + r) * H_DIM + k0 + kk)
                            : (xbf + (size_t)(mb + r) * (T_DIM * I_DIMV)
                                   + (size_t)t * I_DIMV + (k0 - H_DIM) + kk);
                *(short8*)(&Alds[r * 136 + kk]) = *(const short8*)src;
            }
            // stage W tile 64x128
            #pragma unroll
            for (int u = 0; u < 4; ++u) {
                const int idx = tid + u * 256;
                const int r  = idx >> 4;
                const int kk = (idx & 15) * 8;
                *(short8*)(&Wlds[r * 136 + kk]) =
                    *(const short8*)(Wc + (size_t)(p0 + r) * K_TOT + k0 + kk);
            }
            __syncthreads();
            #pragma unroll
            for (int kc = 0; kc < 4; ++kc) {
                const int ko = kc * 32 + quad * 8;
                short8 bfrag = *(const short8*)(&Wlds[(wid * 16 + cl) * 136 + ko]);
                short8 a0    = *(const short8*)(&Alds[cl * 136 + ko]);
                short8 a1    = *(const short8*)(&Alds[(16 + cl) * 136 + ko]);
                acc0 = __builtin_amdgcn_mfma_f32_16x16x32_bf16(a0, bfrag, acc0, 0, 0, 0);
                acc1 = __builtin_amdgcn_mfma_f32_16x16x32_bf16(a1, bfrag, acc1, 0, 0, 0);
            }
        }

        // pointwise LSTM cell. lane holds gates[b = mb+mt*16+quad*4+r][p = p0+wid*16+cl]
        // i/f/g/o for same hidden j sit in 4 adjacent lanes -> 3 shfl_xor gathers.
        #pragma unroll
        for (int mt = 0; mt < 2; ++mt) {
            #pragma unroll
            for (int r = 0; r < 4; ++r) {
                float v  = ((mt == 0) ? acc0[r] : acc1[r]) + bias_lane;
                float x1 = __shfl_xor(v, 1);
                float x2 = __shfl_xor(v, 2);
                float x3 = __shfl_xor(v, 3);
                // value from lane with gate q' = q_g ^ m is {v,x1,x2,x3}[m]
                float iv = (q_g == 0) ? v : (q_g == 1) ? x1 : (q_g == 2) ? x2 : x3;
                int mf = q_g ^ 1;
                float fv = (mf == 0) ? v : (mf == 1) ? x1 : (mf == 2) ? x2 : x3;
                int mg = q_g ^ 2;
                float gv = (mg == 0) ? v : (mg == 1) ? x1 : (mg == 2) ? x2 : x3;
                int mo = q_g ^ 3;
                float ov = (mo == 0) ? v : (mo == 1) ? x1 : (mo == 2) ? x2 : x3;

                float ig = sigmoid_f(iv);
                float fg = sigmoid_f(fv);
                float gg = tanh_f(gv);
                float og = sigmoid_f(ov);
                const int ci = mt * 4 + r;
                float cn = fg * c_reg[ci] + ig * gg;   // all 4 q-lanes compute identically
                c_reg[ci] = cn;
                float hn = og * tanh_f(cn);
                if (q_g == 0) {
                    const int b = mb + mt * 16 + quad * 4 + r;
                    const int j = j0 + wid * 4 + jl;
                    hwrite[(size_t)b * H_DIM + j] = f2bf(hn);
                    if (t == T_DIM - 1) hf32[(size_t)b * H_DIM + j] = hn;
                }
            }
        }
        grid.sync();
    }
}

// ---------------------------------------------------------------------------
// Final fc: out[128,1000] = h @ fc_W^T + fc_b, fp32. Tile 16(b) x 64(o) per WG.
// ---------------------------------------------------------------------------
__global__ __launch_bounds__(256)
void fc_kernel(const float* __restrict__ hf32,
               const float* __restrict__ fcW,
               const float* __restrict__ fcb,
               float* __restrict__ out)
{
    __shared__ __align__(16) float hs[16 * 256];
    const int tid = threadIdx.x;
    const int b0 = blockIdx.x * 16;
    const int o0 = blockIdx.y * 64;
    const int to = tid & 63;
    const int tb = tid >> 6;
    const int o  = o0 + to;
    const bool active = (o < C_DIM);

    float acc[4] = {0.f, 0.f, 0.f, 0.f};

    for (int jc = 0; jc < H_DIM; jc += 256) {
        __syncthreads();
        {
            const int row = tid >> 4;
            const int c0  = (tid & 15) * 16;
            #pragma unroll
            for (int u = 0; u < 4; ++u) {
                *(f32x4*)(&hs[row * 256 + c0 + u * 4]) =
                    *(const f32x4*)(hf32 + (size_t)(b0 + row) * H_DIM + jc + c0 + u * 4);
            }
        }
        __syncthreads();
        if (active) {
            for (int j4 = 0; j4 < 256; j4 += 4) {
                f32x4 wv = *(const f32x4*)(fcW + (size_t)o * H_DIM + jc + j4);
                #pragma unroll
                for (int bb = 0; bb < 4; ++bb) {
                    f32x4 hv = *(const f32x4*)(&hs[(tb * 4 + bb) * 256 + j4]);
                    acc[bb] += wv.x * hv.x + wv.y * hv.y + wv.z * hv.z + wv.w * hv.w;
                }
            }
        }
    }
    if (active) {
        const float bias = fcb[o];
        #pragma unroll
        for (int bb = 0; bb < 4; ++bb) {
            out[(size_t)(b0 + tb * 4 + bb) * C_DIM + o] = acc[bb] + bias;
        }
    }
}

extern "C" void kernel_launch(void* const* d_in, const int* in_sizes, int n_in,
                              void* d_out, int out_size, void* d_ws, size_t ws_size,
                              hipStream_t stream)
{
    const float* x   = (const float*)d_in[0];
    const float* Wih = (const float*)d_in[1];
    const float* Whh = (const float*)d_in[2];
    const float* bih = (const float*)d_in[3];
    const float* bhh = (const float*)d_in[4];
    const float* fcW = (const float*)d_in[5];
    const float* fcb = (const float*)d_in[6];
    float* out = (float*)d_out;

    char* ws = (char*)d_ws;
    unsigned short* Wc  = (unsigned short*)(ws + 0);         // 10,485,760 B
    unsigned short* xbf = (unsigned short*)(ws + 10485760);  // 33,554,432 B
    float* biasc        = (float*)(ws + 44040192);           //     16,384 B
    unsigned short* hb0 = (unsigned short*)(ws + 44056576);  //    262,144 B
    unsigned short* hb1 = (unsigned short*)(ws + 44318720);  //    262,144 B
    float* hf32         = (float*)(ws + 44580864);           //    524,288 B
    // total ws use: 45,105,152 B

    hipLaunchKernelGGL(prep_kernel, dim3(1024), dim3(256), 0, stream,
                       x, Wih, Whh, bih, bhh, Wc, xbf, biasc, hb0);

    void* args[] = {(void*)&Wc, (void*)&xbf, (void*)&biasc,
                    (void*)&hb0, (void*)&hb1, (void*)&hf32};
    hipLaunchCooperativeKernel((void*)lstm_persistent, dim3(256), dim3(256),
                               args, 0, stream);

    hipLaunchKernelGGL(fc_kernel, dim3(8, 16), dim3(256), 0, stream,
                       hf32, fcW, fcb, out);
}

// Round 5
// 8870.593 us; speedup vs baseline: 2.3618x; 2.3618x over previous
//
#include <hip/hip_runtime.h>
#include <hip/hip_bf16.h>

#define B_DIM 128
#define T_DIM 512
#define I_DIMV 256
#define H_DIM 1024
#define G_DIM 4096
#define K_TOT 1280
#define C_DIM 1000
#define A_STRIDE 1288   // 1280 + 8 shorts pad (byte stride 2576, 16B aligned)

typedef __attribute__((ext_vector_type(8))) short short8;
typedef __attribute__((ext_vector_type(4))) float f32x4;
typedef __attribute__((ext_vector_type(4))) unsigned short ushort4v;
typedef __attribute__((ext_vector_type(4))) int int4v;

__device__ __forceinline__ unsigned short f2bf(float f) {
    unsigned int u = __float_as_uint(f);
    u += 0x7FFF + ((u >> 16) & 1);   // round-to-nearest-even
    return (unsigned short)(u >> 16);
}

__device__ __forceinline__ float sigmoid_f(float x) {
    return __builtin_amdgcn_rcpf(1.0f + __expf(-x));
}
__device__ __forceinline__ float tanh_f(float x) {
    return 1.0f - 2.0f * __builtin_amdgcn_rcpf(1.0f + __expf(2.0f * x));
}

// ---------------------------------------------------------------------------
// Prologue: combined bf16 weights (gate-interleaved rows p = j*4+q), bf16 x,
// combined bias, zeroed h0, zeroed barrier state (in d_out!). Runs every call.
// ---------------------------------------------------------------------------
__global__ void prep_kernel(const float* __restrict__ x,
                            const float* __restrict__ Wih,
                            const float* __restrict__ Whh,
                            const float* __restrict__ bih,
                            const float* __restrict__ bhh,
                            unsigned short* __restrict__ Wc,
                            unsigned short* __restrict__ xbf,
                            float* __restrict__ biasc,
                            unsigned short* __restrict__ h0,
                            unsigned* __restrict__ bar)
{
    const int tid = blockIdx.x * blockDim.x + threadIdx.x;
    const int nth = gridDim.x * blockDim.x;

    const int WcN4 = G_DIM * K_TOT / 4;
    for (int i = tid; i < WcN4; i += nth) {
        int p = i / (K_TOT / 4);
        int k = (i - p * (K_TOT / 4)) * 4;
        int j = p >> 2, q = p & 3;
        int r = q * H_DIM + j;
        const float* src = (k < H_DIM) ? (Whh + (size_t)r * H_DIM + k)
                                       : (Wih + (size_t)r * I_DIMV + (k - H_DIM));
        f32x4 v = *(const f32x4*)src;
        ushort4v o;
        o.x = f2bf(v.x); o.y = f2bf(v.y); o.z = f2bf(v.z); o.w = f2bf(v.w);
        *(ushort4v*)(Wc + (size_t)i * 4) = o;
    }
    const int xN4 = B_DIM * T_DIM * I_DIMV / 4;
    for (int i = tid; i < xN4; i += nth) {
        f32x4 v = *(const f32x4*)(x + (size_t)i * 4);
        ushort4v o;
        o.x = f2bf(v.x); o.y = f2bf(v.y); o.z = f2bf(v.z); o.w = f2bf(v.w);
        *(ushort4v*)(xbf + (size_t)i * 4) = o;
    }
    for (int p = tid; p < G_DIM; p += nth) {
        int j = p >> 2, q = p & 3;
        int r = q * H_DIM + j;
        biasc[p] = bih[r] + bhh[r];
    }
    const int hN4 = B_DIM * H_DIM / 4;
    for (int i = tid; i < hN4; i += nth) {
        ushort4v z = {0, 0, 0, 0};
        *(ushort4v*)(h0 + (size_t)i * 4) = z;
    }
    for (int i = tid; i < 1024; i += nth) bar[i] = 0;
}

// ---------------------------------------------------------------------------
// Two-level grid barrier with explicit device fences on BOTH sides.
// Release: __threadfence() (s_waitcnt + buffer_wbl2/inv, device scope)
// before the arrival RMW flushes this XCD's dirty h lines to the MALL.
// Arrival RMWs chain causally to the master's gen release-store. After the
// spin/release, a second __threadfence() invalidates stale L1/L2 lines so
// the next step's PLAIN h loads refetch fresh data from the MALL.
// bar (in d_out): [64*g] g=0..7 leaf counters, [512] master, [576] gen.
// ---------------------------------------------------------------------------
__device__ __forceinline__ void grid_barrier(unsigned* bar, unsigned epoch, int wgid) {
    __syncthreads();   // every wave's h stores drained (vmcnt) to local L2
    if (threadIdx.x == 0) {
        __threadfence();   // RELEASE: write back dirty L2 to coherence point
        unsigned* gcnt = bar + 64 * (wgid & 7);
        unsigned* mcnt = bar + 512;
        unsigned* gen  = bar + 576;
        unsigned old = __hip_atomic_fetch_add(gcnt, 1u, __ATOMIC_RELAXED,
                                              __HIP_MEMORY_SCOPE_AGENT);
        if (old == 31u) {
            unsigned m = __hip_atomic_fetch_add(mcnt, 1u, __ATOMIC_RELAXED,
                                                __HIP_MEMORY_SCOPE_AGENT);
            if (m == 7u) {
                __hip_atomic_store(mcnt, 0u, __ATOMIC_RELAXED,
                                   __HIP_MEMORY_SCOPE_AGENT);
                #pragma unroll
                for (int i = 0; i < 8; ++i)
                    __hip_atomic_store(bar + 64 * i, 0u, __ATOMIC_RELAXED,
                                       __HIP_MEMORY_SCOPE_AGENT);
                __hip_atomic_store(gen, epoch, __ATOMIC_RELEASE,
                                   __HIP_MEMORY_SCOPE_AGENT);
            } else {
                while (__hip_atomic_load(gen, __ATOMIC_RELAXED,
                                         __HIP_MEMORY_SCOPE_AGENT) < epoch)
                    __builtin_amdgcn_s_sleep(1);
            }
        } else {
            while (__hip_atomic_load(gen, __ATOMIC_RELAXED,
                                     __HIP_MEMORY_SCOPE_AGENT) < epoch)
                __builtin_amdgcn_s_sleep(1);
        }
        __threadfence();   // ACQUIRE: invalidate stale L1/L2 before reloads
    }
    __syncthreads();
}

// ---------------------------------------------------------------------------
// Persistent LSTM, PLAIN launch (no cooperative API). 256 WGs x 256 threads.
// Co-residency is structural: LDS 41KB (<160KB/CU) and VGPR<=512 mean every
// CU can host >=1 WG, so all 256 WGs are dispatched immediately across the
// 256 CUs -- no WG waits for another to finish => custom barrier is safe.
// WG: m_blk = wgid>>5 -> batches [16*m_blk, +16)
//     n_blk = wgid&31 -> hidden [32*n_blk, +32) == gate rows [128*n_blk, +128)
// W slice (128 x 1280) in 320 VGPRs/lane for all 512 steps. Full A panel
// (16 x 1280) staged to LDS once per step. c-state in registers.
// ---------------------------------------------------------------------------
__global__ __launch_bounds__(256, 1)
void lstm_grid(const unsigned short* __restrict__ Wc,
               const unsigned short* __restrict__ xbf,
               const float* __restrict__ biasc,
               unsigned short* __restrict__ hb0,
               unsigned short* __restrict__ hb1,
               float* __restrict__ hf32,
               unsigned* __restrict__ bar)
{
    __shared__ __align__(16) unsigned short Alds[16 * A_STRIDE];  // 41,216 B

    const int tid   = threadIdx.x;
    const int wgid  = blockIdx.x;
    const int m_blk = wgid >> 5;
    const int n_blk = wgid & 31;
    const int b0 = m_blk * 16;         // batch rows [b0, b0+16)
    const int p0 = n_blk * 128;        // gate rows  [p0, p0+128)
    const int j0 = n_blk * 32;         // hidden cols [j0, j0+32)

    const int wid  = tid >> 6;         // wave -> gate cols [wid*32, +32)
    const int lane = tid & 63;
    const int cl   = lane & 15;
    const int quad = lane >> 4;
    const int q_g  = cl & 3;           // gate: 0=i 1=f 2=g 3=o
    const int jl   = cl >> 2;

    const float bias0 = biasc[p0 + wid * 32 + cl];
    const float bias1 = biasc[p0 + wid * 32 + 16 + cl];

    // W slice in registers: 2 subtiles x 40 k-chunks = 80 x short8 (320 VGPR)
    short8 Wreg[80];
    {
        const unsigned short* w0 = Wc + (size_t)(p0 + wid * 32 + cl) * K_TOT + quad * 8;
        const unsigned short* w1 = w0 + (size_t)16 * K_TOT;
        #pragma unroll
        for (int c = 0; c < 40; ++c) {
            Wreg[c]      = *(const short8*)(w0 + c * 32);
            Wreg[40 + c] = *(const short8*)(w1 + c * 32);
        }
    }

    float c_reg[8];
    #pragma unroll
    for (int i = 0; i < 8; ++i) c_reg[i] = 0.0f;

    for (int t = 0; t < T_DIM; ++t) {
        const unsigned short* hread = (t & 1) ? hb1 : hb0;
        unsigned short* hwrite      = (t & 1) ? hb0 : hb1;

        // ---- stage A panel: h[16x1024] (sc0, L1-bypass) + x_t[16x256] ----
        int4v htmp[8];
        #pragma unroll
        for (int u = 0; u < 8; ++u) {
            const int idx = u * 256 + tid;          // 0..2047
            const int row = idx >> 7;               // 0..15
            const int col = (idx & 127) * 8;        // 0..1016
            const unsigned short* src = hread + (size_t)(b0 + row) * H_DIM + col;
            asm volatile("global_load_dwordx4 %0, %1, off sc0"
                         : "=v"(htmp[u]) : "v"(src) : "memory");
        }
        short8 xtmp[2];
        #pragma unroll
        for (int u = 0; u < 2; ++u) {
            const int idx = u * 256 + tid;          // 0..511
            const int row = idx >> 5;               // 0..15
            const int col = (idx & 31) * 8;         // 0..248
            xtmp[u] = *(const short8*)(xbf + (size_t)(b0 + row) * (T_DIM * I_DIMV)
                                       + (size_t)t * I_DIMV + col);
        }
        asm volatile("s_waitcnt vmcnt(0)" ::: "memory");
        #pragma unroll
        for (int u = 0; u < 8; ++u) {
            const int idx = u * 256 + tid;
            const int row = idx >> 7;
            const int col = (idx & 127) * 8;
            *(int4v*)(&Alds[row * A_STRIDE + col]) = htmp[u];
        }
        #pragma unroll
        for (int u = 0; u < 2; ++u) {
            const int idx = u * 256 + tid;
            const int row = idx >> 5;
            const int col = (idx & 31) * 8;
            *(short8*)(&Alds[row * A_STRIDE + 1024 + col]) = xtmp[u];
        }
        __syncthreads();

        // ---- K loop: 40 chunks x 2 gate-subtiles, W from registers ----
        f32x4 acc0 = {0.f, 0.f, 0.f, 0.f};
        f32x4 acc1 = {0.f, 0.f, 0.f, 0.f};
        #pragma unroll
        for (int c = 0; c < 40; ++c) {
            short8 a = *(const short8*)(&Alds[cl * A_STRIDE + c * 32 + quad * 8]);
            acc0 = __builtin_amdgcn_mfma_f32_16x16x32_bf16(a, Wreg[c],      acc0, 0, 0, 0);
            acc1 = __builtin_amdgcn_mfma_f32_16x16x32_bf16(a, Wreg[40 + c], acc1, 0, 0, 0);
        }

        // ---- pointwise LSTM cell (R1-verified shfl path) + packed h store ----
        #pragma unroll
        for (int s = 0; s < 2; ++s) {
            const f32x4 accv   = s ? acc1 : acc0;
            const float bias_s = s ? bias1 : bias0;
            #pragma unroll
            for (int r = 0; r < 4; ++r) {
                float v  = accv[r] + bias_s;
                float x1 = __shfl_xor(v, 1);
                float x2 = __shfl_xor(v, 2);
                float x3 = __shfl_xor(v, 3);
                float iv = (q_g == 0) ? v : (q_g == 1) ? x1 : (q_g == 2) ? x2 : x3;
                int mf = q_g ^ 1;
                float fv = (mf == 0) ? v : (mf == 1) ? x1 : (mf == 2) ? x2 : x3;
                int mg = q_g ^ 2;
                float gv = (mg == 0) ? v : (mg == 1) ? x1 : (mg == 2) ? x2 : x3;
                int mo = q_g ^ 3;
                float ov = (mo == 0) ? v : (mo == 1) ? x1 : (mo == 2) ? x2 : x3;

                float ig = sigmoid_f(iv);
                float fg = sigmoid_f(fv);
                float gg = tanh_f(gv);
                float og = sigmoid_f(ov);
                const int ci = s * 4 + r;
                float cn = fg * c_reg[ci] + ig * gg;
                c_reg[ci] = cn;
                float hn = og * tanh_f(cn);

                const int b  = b0 + quad * 4 + r;
                const int jb = j0 + wid * 8 + s * 4;   // j base (jl==0 lane)

                unsigned short hb = f2bf(hn);
                unsigned p32 = (unsigned)hb |
                    ((unsigned)(unsigned short)__shfl_xor((int)hb, 4) << 16);
                unsigned long long p64 = (unsigned long long)p32 |
                    ((unsigned long long)(unsigned)__shfl_xor((int)p32, 8) << 32);
                if (cl == 0) {
                    *(unsigned long long*)(hwrite + (size_t)b * H_DIM + jb) = p64;
                }
                if (t == T_DIM - 1 && q_g == 0) {
                    hf32[(size_t)b * H_DIM + jb + jl] = hn;
                }
            }
        }

        if (t + 1 < T_DIM)
            grid_barrier(bar, (unsigned)(t + 1), wgid);
        // final step: hf32 stores drain at kernel end (dispatch boundary)
    }
}

// ---------------------------------------------------------------------------
// Final fc: out[128,1000] = h @ fc_W^T + fc_b, fp32. Overwrites the bar
// region in d_out with real results (runs strictly after lstm_grid).
// ---------------------------------------------------------------------------
__global__ __launch_bounds__(256)
void fc_kernel(const float* __restrict__ hf32,
               const float* __restrict__ fcW,
               const float* __restrict__ fcb,
               float* __restrict__ out)
{
    __shared__ __align__(16) float hs[16 * 256];
    const int tid = threadIdx.x;
    const int b0 = blockIdx.x * 16;
    const int o0 = blockIdx.y * 64;
    const int to = tid & 63;
    const int tb = tid >> 6;
    const int o  = o0 + to;
    const bool active = (o < C_DIM);

    float acc[4] = {0.f, 0.f, 0.f, 0.f};

    for (int jc = 0; jc < H_DIM; jc += 256) {
        __syncthreads();
        {
            const int row = tid >> 4;
            const int c0  = (tid & 15) * 16;
            #pragma unroll
            for (int u = 0; u < 4; ++u) {
                *(f32x4*)(&hs[row * 256 + c0 + u * 4]) =
                    *(const f32x4*)(hf32 + (size_t)(b0 + row) * H_DIM + jc + c0 + u * 4);
            }
        }
        __syncthreads();
        if (active) {
            for (int j4 = 0; j4 < 256; j4 += 4) {
                f32x4 wv = *(const f32x4*)(fcW + (size_t)o * H_DIM + jc + j4);
                #pragma unroll
                for (int bb = 0; bb < 4; ++bb) {
                    f32x4 hv = *(const f32x4*)(&hs[(tb * 4 + bb) * 256 + j4]);
                    acc[bb] += wv.x * hv.x + wv.y * hv.y + wv.z * hv.z + wv.w * hv.w;
                }
            }
        }
    }
    if (active) {
        const float bias = fcb[o];
        #pragma unroll
        for (int bb = 0; bb < 4; ++bb) {
            out[(size_t)(b0 + tb * 4 + bb) * C_DIM + o] = acc[bb] + bias;
        }
    }
}

extern "C" void kernel_launch(void* const* d_in, const int* in_sizes, int n_in,
                              void* d_out, int out_size, void* d_ws, size_t ws_size,
                              hipStream_t stream)
{
    const float* x   = (const float*)d_in[0];
    const float* Wih = (const float*)d_in[1];
    const float* Whh = (const float*)d_in[2];
    const float* bih = (const float*)d_in[3];
    const float* bhh = (const float*)d_in[4];
    const float* fcW = (const float*)d_in[5];
    const float* fcb = (const float*)d_in[6];
    float* out = (float*)d_out;

    char* ws = (char*)d_ws;
    unsigned short* Wc  = (unsigned short*)(ws + 0);         // 10,485,760 B
    unsigned short* xbf = (unsigned short*)(ws + 10485760);  // 33,554,432 B
    float* biasc        = (float*)(ws + 44040192);           //     16,384 B
    unsigned short* hb0 = (unsigned short*)(ws + 44056576);  //    262,144 B
    unsigned short* hb1 = (unsigned short*)(ws + 44318720);  //    262,144 B
    float* hf32         = (float*)(ws + 44580864);           //    524,288 B
    // total ws use: 45,105,152 B (identical to the R1-proven layout)
    unsigned* bar       = (unsigned*)d_out;  // 4 KB of d_out (512,000 B);
                                             // fc_kernel overwrites it last.

    hipLaunchKernelGGL(prep_kernel, dim3(1024), dim3(256), 0, stream,
                       x, Wih, Whh, bih, bhh, Wc, xbf, biasc, hb0, bar);

    hipLaunchKernelGGL(lstm_grid, dim3(256), dim3(256), 0, stream,
                       Wc, xbf, biasc, hb0, hb1, hf32, bar);

    hipLaunchKernelGGL(fc_kernel, dim3(8, 16), dim3(256), 0, stream,
                       hf32, fcW, fcb, out);
}

// Round 6
// 3370.945 us; speedup vs baseline: 6.2149x; 2.6315x over previous
//
#include <hip/hip_runtime.h>
#include <hip/hip_bf16.h>

#define B_DIM 128
#define T_DIM 512
#define I_DIMV 256
#define H_DIM 1024
#define G_DIM 4096
#define K_TOT 1280
#define C_DIM 1000
#define A_STRIDE 1288   // 1280 + 8 shorts pad (byte stride 2576, 16B aligned)

typedef __attribute__((ext_vector_type(8))) short short8;
typedef __attribute__((ext_vector_type(4))) float f32x4;
typedef __attribute__((ext_vector_type(4))) unsigned short ushort4v;
typedef __attribute__((ext_vector_type(4))) int int4v;

__device__ __forceinline__ unsigned short f2bf(float f) {
    unsigned int u = __float_as_uint(f);
    u += 0x7FFF + ((u >> 16) & 1);   // round-to-nearest-even
    return (unsigned short)(u >> 16);
}

__device__ __forceinline__ float sigmoid_f(float x) {
    return __builtin_amdgcn_rcpf(1.0f + __expf(-x));
}
__device__ __forceinline__ float tanh_f(float x) {
    return 1.0f - 2.0f * __builtin_amdgcn_rcpf(1.0f + __expf(2.0f * x));
}

// ---------------------------------------------------------------------------
// Prologue: combined bf16 weights (gate-interleaved rows p = j*4+q), bf16 x,
// combined bias, zeroed h0, zeroed barrier state (in d_out). Runs every call.
// ---------------------------------------------------------------------------
__global__ void prep_kernel(const float* __restrict__ x,
                            const float* __restrict__ Wih,
                            const float* __restrict__ Whh,
                            const float* __restrict__ bih,
                            const float* __restrict__ bhh,
                            unsigned short* __restrict__ Wc,
                            unsigned short* __restrict__ xbf,
                            float* __restrict__ biasc,
                            unsigned short* __restrict__ h0,
                            unsigned* __restrict__ bar)
{
    const int tid = blockIdx.x * blockDim.x + threadIdx.x;
    const int nth = gridDim.x * blockDim.x;

    const int WcN4 = G_DIM * K_TOT / 4;
    for (int i = tid; i < WcN4; i += nth) {
        int p = i / (K_TOT / 4);
        int k = (i - p * (K_TOT / 4)) * 4;
        int j = p >> 2, q = p & 3;
        int r = q * H_DIM + j;
        const float* src = (k < H_DIM) ? (Whh + (size_t)r * H_DIM + k)
                                       : (Wih + (size_t)r * I_DIMV + (k - H_DIM));
        f32x4 v = *(const f32x4*)src;
        ushort4v o;
        o.x = f2bf(v.x); o.y = f2bf(v.y); o.z = f2bf(v.z); o.w = f2bf(v.w);
        *(ushort4v*)(Wc + (size_t)i * 4) = o;
    }
    const int xN4 = B_DIM * T_DIM * I_DIMV / 4;
    for (int i = tid; i < xN4; i += nth) {
        f32x4 v = *(const f32x4*)(x + (size_t)i * 4);
        ushort4v o;
        o.x = f2bf(v.x); o.y = f2bf(v.y); o.z = f2bf(v.z); o.w = f2bf(v.w);
        *(ushort4v*)(xbf + (size_t)i * 4) = o;
    }
    for (int p = tid; p < G_DIM; p += nth) {
        int j = p >> 2, q = p & 3;
        int r = q * H_DIM + j;
        biasc[p] = bih[r] + bhh[r];
    }
    const int hN4 = B_DIM * H_DIM / 4;
    for (int i = tid; i < hN4; i += nth) {
        ushort4v z = {0, 0, 0, 0};
        *(ushort4v*)(h0 + (size_t)i * 4) = z;
    }
    for (int i = tid; i < 1024; i += nth) bar[i] = 0;
}

// ---------------------------------------------------------------------------
// Per-group 32-way barrier (batch groups are data-independent; only the 32
// WGs sharing batch rows [16g,16g+16) must sync). No cache maintenance:
// all shared data (h) moves via sc0+sc1 (MALL-direct) accesses, and
// __syncthreads' vmcnt drain orders h stores before the arrival RMW.
// bar (in d_out): per group g: [64g] counter, [64g+32] generation.
// ---------------------------------------------------------------------------
__device__ __forceinline__ void group_barrier(unsigned* bar, unsigned epoch, int grp) {
    __syncthreads();   // every wave's sc0sc1 h stores acked at the MALL
    if (threadIdx.x == 0) {
        unsigned* cnt = bar + 64 * grp;
        unsigned* gen = bar + 64 * grp + 32;
        unsigned old = __hip_atomic_fetch_add(cnt, 1u, __ATOMIC_RELAXED,
                                              __HIP_MEMORY_SCOPE_AGENT);
        if (old == 31u) {   // last arriver: reset + release generation
            __hip_atomic_store(cnt, 0u, __ATOMIC_RELAXED,
                               __HIP_MEMORY_SCOPE_AGENT);
            __hip_atomic_store(gen, epoch, __ATOMIC_RELEASE,
                               __HIP_MEMORY_SCOPE_AGENT);
        } else {
            while (__hip_atomic_load(gen, __ATOMIC_RELAXED,
                                     __HIP_MEMORY_SCOPE_AGENT) < epoch)
                __builtin_amdgcn_s_sleep(1);
        }
    }
    __syncthreads();
}

// ---------------------------------------------------------------------------
// Persistent LSTM, plain launch. 256 WGs x 256 threads; co-residency is
// structural (LDS 41KB, <=1 WG/CU by VGPR budget; 256 WGs on 256 CUs -> all
// dispatched immediately, no WG waits on another's completion).
// WG: m_blk = wgid>>5 -> batches [16*m_blk, +16) (= sync group)
//     n_blk = wgid&31 -> hidden [32*n_blk, +32) == gate rows [128*n_blk,+128)
// W slice in registers for all 512 steps. h exchanged MALL-direct (sc0 sc1).
// ---------------------------------------------------------------------------
__global__ __launch_bounds__(256, 1)
void lstm_grid(const unsigned short* __restrict__ Wc,
               const unsigned short* __restrict__ xbf,
               const float* __restrict__ biasc,
               unsigned short* __restrict__ hb0,
               unsigned short* __restrict__ hb1,
               float* __restrict__ hf32,
               unsigned* __restrict__ bar)
{
    __shared__ __align__(16) unsigned short Alds[16 * A_STRIDE];  // 41,216 B

    const int tid   = threadIdx.x;
    const int wgid  = blockIdx.x;
    const int m_blk = wgid >> 5;
    const int n_blk = wgid & 31;
    const int b0 = m_blk * 16;         // batch rows [b0, b0+16)
    const int p0 = n_blk * 128;        // gate rows  [p0, p0+128)
    const int j0 = n_blk * 32;         // hidden cols [j0, j0+32)

    const int wid  = tid >> 6;         // wave -> gate cols [wid*32, +32)
    const int lane = tid & 63;
    const int cl   = lane & 15;
    const int quad = lane >> 4;
    const int q_g  = cl & 3;           // gate: 0=i 1=f 2=g 3=o
    const int jl   = cl >> 2;

    const float bias0 = biasc[p0 + wid * 32 + cl];
    const float bias1 = biasc[p0 + wid * 32 + 16 + cl];

    // W slice in registers: 2 subtiles x 40 k-chunks = 80 x short8 (320 regs)
    short8 Wreg[80];
    {
        const unsigned short* w0 = Wc + (size_t)(p0 + wid * 32 + cl) * K_TOT + quad * 8;
        const unsigned short* w1 = w0 + (size_t)16 * K_TOT;
        #pragma unroll
        for (int c = 0; c < 40; ++c) {
            Wreg[c]      = *(const short8*)(w0 + c * 32);
            Wreg[40 + c] = *(const short8*)(w1 + c * 32);
        }
    }

    float c_reg[8];
    #pragma unroll
    for (int i = 0; i < 8; ++i) c_reg[i] = 0.0f;

    for (int t = 0; t < T_DIM; ++t) {
        const unsigned short* hread = (t & 1) ? hb1 : hb0;
        unsigned short* hwrite      = (t & 1) ? hb0 : hb1;

        // ---- stage A panel: h[16x1024] MALL-direct + x_t[16x256] cached ----
        int4v htmp[8];
        #pragma unroll
        for (int u = 0; u < 8; ++u) {
            const int idx = u * 256 + tid;          // 0..2047
            const int row = idx >> 7;               // 0..15
            const int col = (idx & 127) * 8;        // 0..1016
            const unsigned short* src = hread + (size_t)(b0 + row) * H_DIM + col;
            asm volatile("global_load_dwordx4 %0, %1, off sc0 sc1"
                         : "=v"(htmp[u]) : "v"(src) : "memory");
        }
        short8 xtmp[2];
        #pragma unroll
        for (int u = 0; u < 2; ++u) {
            const int idx = u * 256 + tid;          // 0..511
            const int row = idx >> 5;               // 0..15
            const int col = (idx & 31) * 8;         // 0..248
            xtmp[u] = *(const short8*)(xbf + (size_t)(b0 + row) * (T_DIM * I_DIMV)
                                       + (size_t)t * I_DIMV + col);
        }
        asm volatile("s_waitcnt vmcnt(0)" ::: "memory");
        #pragma unroll
        for (int u = 0; u < 8; ++u) {
            const int idx = u * 256 + tid;
            const int row = idx >> 7;
            const int col = (idx & 127) * 8;
            *(int4v*)(&Alds[row * A_STRIDE + col]) = htmp[u];
        }
        #pragma unroll
        for (int u = 0; u < 2; ++u) {
            const int idx = u * 256 + tid;
            const int row = idx >> 5;
            const int col = (idx & 31) * 8;
            *(short8*)(&Alds[row * A_STRIDE + 1024 + col]) = xtmp[u];
        }
        __syncthreads();

        // ---- K loop: 40 chunks x 2 gate-subtiles, W from registers ----
        f32x4 acc0 = {0.f, 0.f, 0.f, 0.f};
        f32x4 acc1 = {0.f, 0.f, 0.f, 0.f};
        #pragma unroll
        for (int c = 0; c < 40; ++c) {
            short8 a = *(const short8*)(&Alds[cl * A_STRIDE + c * 32 + quad * 8]);
            acc0 = __builtin_amdgcn_mfma_f32_16x16x32_bf16(a, Wreg[c],      acc0, 0, 0, 0);
            acc1 = __builtin_amdgcn_mfma_f32_16x16x32_bf16(a, Wreg[40 + c], acc1, 0, 0, 0);
        }

        // ---- pointwise LSTM cell + packed MALL-direct h store ----
        #pragma unroll
        for (int s = 0; s < 2; ++s) {
            const f32x4 accv   = s ? acc1 : acc0;
            const float bias_s = s ? bias1 : bias0;
            #pragma unroll
            for (int r = 0; r < 4; ++r) {
                float v  = accv[r] + bias_s;
                float x1 = __shfl_xor(v, 1);
                float x2 = __shfl_xor(v, 2);
                float x3 = __shfl_xor(v, 3);
                float iv = (q_g == 0) ? v : (q_g == 1) ? x1 : (q_g == 2) ? x2 : x3;
                int mf = q_g ^ 1;
                float fv = (mf == 0) ? v : (mf == 1) ? x1 : (mf == 2) ? x2 : x3;
                int mg = q_g ^ 2;
                float gv = (mg == 0) ? v : (mg == 1) ? x1 : (mg == 2) ? x2 : x3;
                int mo = q_g ^ 3;
                float ov = (mo == 0) ? v : (mo == 1) ? x1 : (mo == 2) ? x2 : x3;

                float ig = sigmoid_f(iv);
                float fg = sigmoid_f(fv);
                float gg = tanh_f(gv);
                float og = sigmoid_f(ov);
                const int ci = s * 4 + r;
                float cn = fg * c_reg[ci] + ig * gg;
                c_reg[ci] = cn;
                float hn = og * tanh_f(cn);

                const int b  = b0 + quad * 4 + r;
                const int jb = j0 + wid * 8 + s * 4;   // j base (jl==0 lane)

                unsigned short hb = f2bf(hn);
                unsigned p32 = (unsigned)hb |
                    ((unsigned)(unsigned short)__shfl_xor((int)hb, 4) << 16);
                unsigned long long p64 = (unsigned long long)p32 |
                    ((unsigned long long)(unsigned)__shfl_xor((int)p32, 8) << 32);
                if (cl == 0) {
                    unsigned long long* dst =
                        (unsigned long long*)(hwrite + (size_t)b * H_DIM + jb);
                    asm volatile("global_store_dwordx2 %0, %1, off sc0 sc1"
                                 :: "v"(dst), "v"(p64) : "memory");
                }
                if (t == T_DIM - 1 && q_g == 0) {
                    hf32[(size_t)b * H_DIM + jb + jl] = hn;
                }
            }
        }

        if (t + 1 < T_DIM)
            group_barrier(bar, (unsigned)(t + 1), m_blk);
        // final step: hf32 stores drain at kernel end (dispatch boundary)
    }
}

// ---------------------------------------------------------------------------
// Final fc: out[128,1000] = h @ fc_W^T + fc_b, fp32. Overwrites the bar
// region of d_out with real results (runs strictly after lstm_grid).
// ---------------------------------------------------------------------------
__global__ __launch_bounds__(256)
void fc_kernel(const float* __restrict__ hf32,
               const float* __restrict__ fcW,
               const float* __restrict__ fcb,
               float* __restrict__ out)
{
    __shared__ __align__(16) float hs[16 * 256];
    const int tid = threadIdx.x;
    const int b0 = blockIdx.x * 16;
    const int o0 = blockIdx.y * 64;
    const int to = tid & 63;
    const int tb = tid >> 6;
    const int o  = o0 + to;
    const bool active = (o < C_DIM);

    float acc[4] = {0.f, 0.f, 0.f, 0.f};

    for (int jc = 0; jc < H_DIM; jc += 256) {
        __syncthreads();
        {
            const int row = tid >> 4;
            const int c0  = (tid & 15) * 16;
            #pragma unroll
            for (int u = 0; u < 4; ++u) {
                *(f32x4*)(&hs[row * 256 + c0 + u * 4]) =
                    *(const f32x4*)(hf32 + (size_t)(b0 + row) * H_DIM + jc + c0 + u * 4);
            }
        }
        __syncthreads();
        if (active) {
            for (int j4 = 0; j4 < 256; j4 += 4) {
                f32x4 wv = *(const f32x4*)(fcW + (size_t)o * H_DIM + jc + j4);
                #pragma unroll
                for (int bb = 0; bb < 4; ++bb) {
                    f32x4 hv = *(const f32x4*)(&hs[(tb * 4 + bb) * 256 + j4]);
                    acc[bb] += wv.x * hv.x + wv.y * hv.y + wv.z * hv.z + wv.w * hv.w;
                }
            }
        }
    }
    if (active) {
        const float bias = fcb[o];
        #pragma unroll
        for (int bb = 0; bb < 4; ++bb) {
            out[(size_t)(b0 + tb * 4 + bb) * C_DIM + o] = acc[bb] + bias;
        }
    }
}

extern "C" void kernel_launch(void* const* d_in, const int* in_sizes, int n_in,
                              void* d_out, int out_size, void* d_ws, size_t ws_size,
                              hipStream_t stream)
{
    const float* x   = (const float*)d_in[0];
    const float* Wih = (const float*)d_in[1];
    const float* Whh = (const float*)d_in[2];
    const float* bih = (const float*)d_in[3];
    const float* bhh = (const float*)d_in[4];
    const float* fcW = (const float*)d_in[5];
    const float* fcb = (const float*)d_in[6];
    float* out = (float*)d_out;

    char* ws = (char*)d_ws;
    unsigned short* Wc  = (unsigned short*)(ws + 0);         // 10,485,760 B
    unsigned short* xbf = (unsigned short*)(ws + 10485760);  // 33,554,432 B
    float* biasc        = (float*)(ws + 44040192);           //     16,384 B
    unsigned short* hb0 = (unsigned short*)(ws + 44056576);  //    262,144 B
    unsigned short* hb1 = (unsigned short*)(ws + 44318720);  //    262,144 B
    float* hf32         = (float*)(ws + 44580864);           //    524,288 B
    // total ws use: 45,105,152 B (identical to the proven R5 layout)
    unsigned* bar       = (unsigned*)d_out;  // 4 KB of d_out (512,000 B);
                                             // fc_kernel overwrites it last.

    hipLaunchKernelGGL(prep_kernel, dim3(1024), dim3(256), 0, stream,
                       x, Wih, Whh, bih, bhh, Wc, xbf, biasc, hb0, bar);

    hipLaunchKernelGGL(lstm_grid, dim3(256), dim3(256), 0, stream,
                       Wc, xbf, biasc, hb0, hb1, hf32, bar);

    hipLaunchKernelGGL(fc_kernel, dim3(8, 16), dim3(256), 0, stream,
                       hf32, fcW, fcb, out);
}